// Round 1
// baseline (27700.891 us; speedup 1.0000x reference)
//
#include <hip/hip_runtime.h>

// ---------------------------------------------------------------------------
// Problem constants (B=16, N=128, FIN=D=512)
// ---------------------------------------------------------------------------
#define BATCH 16
#define NNODE 128
#define DIM 512
#define NP1 129              // N+1 (with virtual node)
#define EDSZ (NP1 * NP1)     // 16641 per batch
#define LSN 256              // LSAP problem size (n+m)
#define INF_COST 10000.0

// ---------------------------------------------------------------------------
// GEMM (NT): Y[m][n] = relu( sum_k A[m][k] * W[n][k] + bias[n] )
// 64x64 tile, BK=16, 256 threads, 4x4 microtile. M,N,K multiples of 64/16.
// ---------------------------------------------------------------------------
__global__ __launch_bounds__(256) void gemm_nt_relu(
    const float* __restrict__ A, const float* __restrict__ W,
    const float* __restrict__ bias, float* __restrict__ Y,
    int M, int N, int K) {
  __shared__ float sA[16][65];
  __shared__ float sB[16][65];
  const int tid = threadIdx.x;
  const int m0 = blockIdx.x * 64;
  const int n0 = blockIdx.y * 64;
  const int tm = tid / 16, tn = tid % 16;
  const int lr = tid / 4;          // 0..63 (tile row)
  const int lk = (tid % 4) * 4;    // 0,4,8,12 (k offset)
  float acc[4][4] = {};
  for (int k0 = 0; k0 < K; k0 += 16) {
    float4 av = *(const float4*)(A + (size_t)(m0 + lr) * K + k0 + lk);
    float4 wv = *(const float4*)(W + (size_t)(n0 + lr) * K + k0 + lk);
    sA[lk + 0][lr] = av.x; sA[lk + 1][lr] = av.y;
    sA[lk + 2][lr] = av.z; sA[lk + 3][lr] = av.w;
    sB[lk + 0][lr] = wv.x; sB[lk + 1][lr] = wv.y;
    sB[lk + 2][lr] = wv.z; sB[lk + 3][lr] = wv.w;
    __syncthreads();
#pragma unroll
    for (int k = 0; k < 16; ++k) {
      float a[4], b[4];
#pragma unroll
      for (int q = 0; q < 4; ++q) { a[q] = sA[k][tm * 4 + q]; b[q] = sB[k][tn * 4 + q]; }
#pragma unroll
      for (int i = 0; i < 4; ++i)
#pragma unroll
        for (int j = 0; j < 4; ++j) acc[i][j] = fmaf(a[i], b[j], acc[i][j]);
    }
    __syncthreads();
  }
#pragma unroll
  for (int i = 0; i < 4; ++i) {
    int m = m0 + tm * 4 + i;
#pragma unroll
    for (int j = 0; j < 4; ++j) {
      int n = n0 + tn * 4 + j;
      Y[(size_t)m * N + n] = fmaxf(acc[i][j] + bias[n], 0.f);
    }
  }
}

// ---------------------------------------------------------------------------
// Single-row embed (virtual node): y[n] = relu(sum_k x[k]*W[n][k] + b[n])
// ---------------------------------------------------------------------------
__global__ __launch_bounds__(256) void vec_gemm_relu(
    const float* __restrict__ x, const float* __restrict__ W,
    const float* __restrict__ bias, float* __restrict__ y) {
  __shared__ float sx[DIM];
  for (int k = threadIdx.x; k < DIM; k += 256) sx[k] = x[k];
  __syncthreads();
  for (int n = threadIdx.x; n < DIM; n += 256) {
    const float* w = W + (size_t)n * DIM;
    float s = 0.f;
    for (int k = 0; k < DIM; k += 4) {
      float4 wv = *(const float4*)(w + k);
      s = fmaf(sx[k + 0], wv.x, s);
      s = fmaf(sx[k + 1], wv.y, s);
      s = fmaf(sx[k + 2], wv.z, s);
      s = fmaf(sx[k + 3], wv.w, s);
    }
    y[n] = fmaxf(s + bias[n], 0.f);
  }
}

// ---------------------------------------------------------------------------
// cdist: d[b][i][j] = || esrow(b,i) - etrow(b,j) ||_2 , i,j in [0,129)
// row 128 = virtual embedding. 32x32 tile per block, grid (5,5,16).
// ---------------------------------------------------------------------------
__global__ __launch_bounds__(256) void cdist_kernel(
    const float* __restrict__ es, const float* __restrict__ et,
    const float* __restrict__ ev, float* __restrict__ d) {
  const int b = blockIdx.z;
  const int i0 = blockIdx.x * 32;
  const int j0 = blockIdx.y * 32;
  __shared__ float sA[32][33];
  __shared__ float sB[32][33];
  const int tid = threadIdx.x;
  const int ty = tid / 16, tx = tid % 16;
  const int lr = tid / 8;          // 0..31
  const int lk4 = (tid % 8) * 4;   // 0..28
  const int gi = i0 + lr;
  const int gj = j0 + lr;
  const float* pa = (gi < NNODE) ? (es + ((size_t)b * NNODE + gi) * DIM) : ev;
  const float* pb = (gj < NNODE) ? (et + ((size_t)b * NNODE + gj) * DIM) : ev;
  float acc[2][2] = {};
  for (int k0 = 0; k0 < DIM; k0 += 32) {
    float4 av = *(const float4*)(pa + k0 + lk4);
    float4 bv = *(const float4*)(pb + k0 + lk4);
    sA[lr][lk4 + 0] = av.x; sA[lr][lk4 + 1] = av.y;
    sA[lr][lk4 + 2] = av.z; sA[lr][lk4 + 3] = av.w;
    sB[lr][lk4 + 0] = bv.x; sB[lr][lk4 + 1] = bv.y;
    sB[lr][lk4 + 2] = bv.z; sB[lr][lk4 + 3] = bv.w;
    __syncthreads();
#pragma unroll 8
    for (int k = 0; k < 32; ++k) {
      float a0 = sA[ty * 2 + 0][k], a1 = sA[ty * 2 + 1][k];
      float b0 = sB[tx * 2 + 0][k], b1 = sB[tx * 2 + 1][k];
      float d00 = a0 - b0, d01 = a0 - b1, d10 = a1 - b0, d11 = a1 - b1;
      acc[0][0] = fmaf(d00, d00, acc[0][0]);
      acc[0][1] = fmaf(d01, d01, acc[0][1]);
      acc[1][0] = fmaf(d10, d10, acc[1][0]);
      acc[1][1] = fmaf(d11, d11, acc[1][1]);
    }
    __syncthreads();
  }
#pragma unroll
  for (int i = 0; i < 2; ++i) {
    int gi2 = i0 + ty * 2 + i;
#pragma unroll
    for (int j = 0; j < 2; ++j) {
      int gj2 = j0 + tx * 2 + j;
      if (gi2 < NP1 && gj2 < NP1)
        d[(size_t)b * EDSZ + gi2 * NP1 + gj2] = sqrtf(acc[i][j]);
    }
  }
}

// ---------------------------------------------------------------------------
// Deterministic per-batch sum of d (fp64 tree) -> sums[b]
// ---------------------------------------------------------------------------
__global__ __launch_bounds__(256) void batch_sum(
    const float* __restrict__ d, float* __restrict__ sums) {
  const int b = blockIdx.x;
  double s = 0.0;
  for (int idx = threadIdx.x; idx < EDSZ; idx += 256)
    s += (double)d[(size_t)b * EDSZ + idx];
  __shared__ double red[256];
  red[threadIdx.x] = s;
  __syncthreads();
  for (int off = 128; off; off >>= 1) {
    if (threadIdx.x < off) red[threadIdx.x] += red[threadIdx.x + off];
    __syncthreads();
  }
  if (threadIdx.x == 0) sums[b] = (float)red[0];
}

// ---------------------------------------------------------------------------
// normalize: edit = d / sum[b] * N*N
// ---------------------------------------------------------------------------
__global__ __launch_bounds__(256) void normalize_kernel(
    const float* __restrict__ d, const float* __restrict__ sums,
    float* __restrict__ edit) {
  int idx = blockIdx.x * 256 + threadIdx.x;
  if (idx < BATCH * EDSZ) {
    int b = idx / EDSZ;
    edit[idx] = d[idx] / sums[b] * (float)(NNODE * NNODE);
  }
}

// ---------------------------------------------------------------------------
// LSAPE via Jonker-Volgenant shortest augmenting path, 1 block per batch.
// 256 threads: thread t owns column j = t+1 (1-indexed). fp64 state in LDS.
// Cost matrix C (256x256) computed on the fly from edit (129x129):
//   r<128,c<128 : ec[r][c]
//   r<128,c>=128: (c-128==r) ? ec[r][128] : INF
//   r>=128,c<128: (r-128==c) ? ec[128][c] : INF
//   else        : 0
// Writes A (0/1 floats) and geds[b] = sum(A*edit)/256.
// ---------------------------------------------------------------------------
__global__ __launch_bounds__(256) void lsap_kernel(
    const float* __restrict__ edit, float* __restrict__ Aout,
    float* __restrict__ geds) {
  const int b = blockIdx.x;
  const float* ec = edit + (size_t)b * EDSZ;
  float* A = Aout + (size_t)b * EDSZ;
  const int t = threadIdx.x;
  const int j = t + 1;  // column 1..256

  __shared__ double u[LSN + 1], v[LSN + 1], minv[LSN + 1];
  __shared__ int p[LSN + 1], way[LSN + 1];
  __shared__ unsigned char used[LSN + 1];
  __shared__ double s_delta;
  __shared__ int s_j0, s_i0;
  __shared__ double red_v[4];
  __shared__ int red_j[4];

  // zero the A output region for this batch
  for (int idx = t; idx < EDSZ; idx += 256) A[idx] = 0.f;

  u[j] = 0.0; v[j] = 0.0; p[j] = 0; way[j] = 0; used[j] = 0;
  if (t == 0) { u[0] = 0.0; v[0] = 0.0; p[0] = 0; way[0] = 0; used[0] = 0; }
  __syncthreads();

  for (int i = 1; i <= LSN; ++i) {
    if (t == 0) { p[0] = i; s_j0 = 0; }
    minv[j] = 1.0e300;
    used[j] = 0;
    if (t == 0) used[0] = 0;
    __syncthreads();

    for (int iter = 0; iter <= LSN; ++iter) {  // bounded safety; breaks earlier
      if (t == 0) {
        int j0 = s_j0;
        used[j0] = 1;
        s_i0 = p[j0];
      }
      __syncthreads();  // (1)
      const int i0 = s_i0;
      const int j0 = s_j0;
      double cand;
      if (!used[j]) {
        const int r = i0 - 1, c = j - 1;
        double Cv;
        if (r < NNODE) {
          if (c < NNODE) Cv = (double)ec[r * NP1 + c];
          else Cv = (c - NNODE == r) ? (double)ec[r * NP1 + NNODE] : INF_COST;
        } else {
          if (c < NNODE) Cv = (r - NNODE == c) ? (double)ec[NNODE * NP1 + c] : INF_COST;
          else Cv = 0.0;
        }
        double cur = Cv - u[i0] - v[j];
        if (cur < minv[j]) { minv[j] = cur; way[j] = j0; }
        cand = minv[j];
      } else {
        cand = 1.0e300;
      }
      // block-wide argmin with lowest-index tie-break (matches np.argmin)
      double bv = cand; int bj = j;
      for (int off = 32; off; off >>= 1) {
        double ov = __shfl_down(bv, off);
        int oj = __shfl_down(bj, off);
        if (ov < bv || (ov == bv && oj < bj)) { bv = ov; bj = oj; }
      }
      const int w = t >> 6;
      if ((t & 63) == 0) { red_v[w] = bv; red_j[w] = bj; }
      __syncthreads();  // (2)
      if (t == 0) {
        double dv = red_v[0]; int dj = red_j[0];
#pragma unroll
        for (int q = 1; q < 4; ++q)
          if (red_v[q] < dv || (red_v[q] == dv && red_j[q] < dj)) { dv = red_v[q]; dj = red_j[q]; }
        s_delta = dv;
        s_j0 = dj;  // j1
      }
      __syncthreads();  // (3)
      const double delta = s_delta;
      const int j1 = s_j0;
      if (used[j]) { u[p[j]] += delta; v[j] -= delta; }
      else minv[j] -= delta;
      if (t == 0) { u[p[0]] += delta; v[0] -= delta; }  // column 0 (always used)
      __syncthreads();  // (4)
      if (p[j1] == 0) break;
    }
    // augment (serial, thread 0)
    if (t == 0) {
      int j0 = s_j0;
      do {
        int jp = way[j0];
        p[j0] = p[jp];
        j0 = jp;
      } while (j0 != 0);
    }
    __syncthreads();
  }

  // Build A and geds. Column c=j-1 is assigned row r=p[j]-1.
  const int r = p[j] - 1;
  const int ar = min(r, NNODE);
  const int ac = min(j - 1, NNODE);
  double contrib = 0.0;
  if (!(ar == NNODE && ac == NNODE)) {
    A[ar * NP1 + ac] = 1.0f;
    contrib = (double)ec[ar * NP1 + ac];
  }
  double cs = contrib;
  for (int off = 32; off; off >>= 1) cs += __shfl_down(cs, off);
  if ((t & 63) == 0) red_v[t >> 6] = cs;
  __syncthreads();
  if (t == 0)
    geds[b] = (float)((red_v[0] + red_v[1] + red_v[2] + red_v[3]) / 256.0);
}

// ---------------------------------------------------------------------------
// launch
// ---------------------------------------------------------------------------
extern "C" void kernel_launch(void* const* d_in, const int* in_sizes, int n_in,
                              void* d_out, int out_size, void* d_ws, size_t ws_size,
                              hipStream_t stream) {
  const float* x_s  = (const float*)d_in[0];
  const float* x_t  = (const float*)d_in[1];
  const float* W1   = (const float*)d_in[2];
  const float* b1   = (const float*)d_in[3];
  const float* W2   = (const float*)d_in[4];
  const float* b2   = (const float*)d_in[5];
  const float* virt = (const float*)d_in[6];

  const int M = BATCH * NNODE;  // 2048

  float* ws    = (float*)d_ws;
  float* h_s   = ws;                       // 2048*512
  float* h_t   = h_s + (size_t)M * DIM;
  float* e_s   = h_t + (size_t)M * DIM;
  float* e_t   = e_s + (size_t)M * DIM;
  float* h_v   = e_t + (size_t)M * DIM;    // 512
  float* e_v   = h_v + DIM;                // 512
  float* d_raw = e_v + DIM;                // 16*16641
  float* sums  = d_raw + (size_t)BATCH * EDSZ;  // 16

  float* Aout = (float*)d_out;
  float* edit = Aout + (size_t)BATCH * EDSZ;
  float* geds = edit + (size_t)BATCH * EDSZ;

  dim3 gblk(M / 64, DIM / 64);  // (32, 8)
  gemm_nt_relu<<<gblk, 256, 0, stream>>>(x_s, W1, b1, h_s, M, DIM, DIM);
  gemm_nt_relu<<<gblk, 256, 0, stream>>>(x_t, W1, b1, h_t, M, DIM, DIM);
  vec_gemm_relu<<<1, 256, 0, stream>>>(virt, W1, b1, h_v);
  gemm_nt_relu<<<gblk, 256, 0, stream>>>(h_s, W2, b2, e_s, M, DIM, DIM);
  gemm_nt_relu<<<gblk, 256, 0, stream>>>(h_t, W2, b2, e_t, M, DIM, DIM);
  vec_gemm_relu<<<1, 256, 0, stream>>>(h_v, W2, b2, e_v);

  cdist_kernel<<<dim3(5, 5, BATCH), 256, 0, stream>>>(e_s, e_t, e_v, d_raw);
  batch_sum<<<BATCH, 256, 0, stream>>>(d_raw, sums);
  normalize_kernel<<<(BATCH * EDSZ + 255) / 256, 256, 0, stream>>>(d_raw, sums, edit);
  lsap_kernel<<<BATCH, 256, 0, stream>>>(edit, Aout, geds);
}

// Round 2
// 15054.410 us; speedup vs baseline: 1.8401x; 1.8401x over previous
//
#include <hip/hip_runtime.h>

// ---------------------------------------------------------------------------
// Problem constants (B=16, N=128, FIN=D=512)
// ---------------------------------------------------------------------------
#define BATCH 16
#define NNODE 128
#define DIM 512
#define NP1 129              // N+1 (with virtual node)
#define EDSZ (NP1 * NP1)     // 16641 per batch
#define LSN 256              // LSAP problem size (n+m)
#define INF_COST 10000.0
#define ECS_LD 132           // LDS row stride (multiple of 4 for b128 alignment)

// ---------------------------------------------------------------------------
// GEMM (NT): Y[m][n] = relu( sum_k A[m][k] * W[n][k] + bias[n] )
// ---------------------------------------------------------------------------
__global__ __launch_bounds__(256) void gemm_nt_relu(
    const float* __restrict__ A, const float* __restrict__ W,
    const float* __restrict__ bias, float* __restrict__ Y,
    int M, int N, int K) {
  __shared__ float sA[16][65];
  __shared__ float sB[16][65];
  const int tid = threadIdx.x;
  const int m0 = blockIdx.x * 64;
  const int n0 = blockIdx.y * 64;
  const int tm = tid / 16, tn = tid % 16;
  const int lr = tid / 4;
  const int lk = (tid % 4) * 4;
  float acc[4][4] = {};
  for (int k0 = 0; k0 < K; k0 += 16) {
    float4 av = *(const float4*)(A + (size_t)(m0 + lr) * K + k0 + lk);
    float4 wv = *(const float4*)(W + (size_t)(n0 + lr) * K + k0 + lk);
    sA[lk + 0][lr] = av.x; sA[lk + 1][lr] = av.y;
    sA[lk + 2][lr] = av.z; sA[lk + 3][lr] = av.w;
    sB[lk + 0][lr] = wv.x; sB[lk + 1][lr] = wv.y;
    sB[lk + 2][lr] = wv.z; sB[lk + 3][lr] = wv.w;
    __syncthreads();
#pragma unroll
    for (int k = 0; k < 16; ++k) {
      float a[4], b[4];
#pragma unroll
      for (int q = 0; q < 4; ++q) { a[q] = sA[k][tm * 4 + q]; b[q] = sB[k][tn * 4 + q]; }
#pragma unroll
      for (int i = 0; i < 4; ++i)
#pragma unroll
        for (int j = 0; j < 4; ++j) acc[i][j] = fmaf(a[i], b[j], acc[i][j]);
    }
    __syncthreads();
  }
#pragma unroll
  for (int i = 0; i < 4; ++i) {
    int m = m0 + tm * 4 + i;
#pragma unroll
    for (int j = 0; j < 4; ++j) {
      int n = n0 + tn * 4 + j;
      Y[(size_t)m * N + n] = fmaxf(acc[i][j] + bias[n], 0.f);
    }
  }
}

// ---------------------------------------------------------------------------
// Single-row embed (virtual node)
// ---------------------------------------------------------------------------
__global__ __launch_bounds__(256) void vec_gemm_relu(
    const float* __restrict__ x, const float* __restrict__ W,
    const float* __restrict__ bias, float* __restrict__ y) {
  __shared__ float sx[DIM];
  for (int k = threadIdx.x; k < DIM; k += 256) sx[k] = x[k];
  __syncthreads();
  for (int n = threadIdx.x; n < DIM; n += 256) {
    const float* w = W + (size_t)n * DIM;
    float s = 0.f;
    for (int k = 0; k < DIM; k += 4) {
      float4 wv = *(const float4*)(w + k);
      s = fmaf(sx[k + 0], wv.x, s);
      s = fmaf(sx[k + 1], wv.y, s);
      s = fmaf(sx[k + 2], wv.z, s);
      s = fmaf(sx[k + 3], wv.w, s);
    }
    y[n] = fmaxf(s + bias[n], 0.f);
  }
}

// ---------------------------------------------------------------------------
// cdist: d[b][i][j] = || esrow(b,i) - etrow(b,j) ||_2
// ---------------------------------------------------------------------------
__global__ __launch_bounds__(256) void cdist_kernel(
    const float* __restrict__ es, const float* __restrict__ et,
    const float* __restrict__ ev, float* __restrict__ d) {
  const int b = blockIdx.z;
  const int i0 = blockIdx.x * 32;
  const int j0 = blockIdx.y * 32;
  __shared__ float sA[32][33];
  __shared__ float sB[32][33];
  const int tid = threadIdx.x;
  const int ty = tid / 16, tx = tid % 16;
  const int lr = tid / 8;
  const int lk4 = (tid % 8) * 4;
  const int gi = i0 + lr;
  const int gj = j0 + lr;
  const float* pa = (gi < NNODE) ? (es + ((size_t)b * NNODE + gi) * DIM) : ev;
  const float* pb = (gj < NNODE) ? (et + ((size_t)b * NNODE + gj) * DIM) : ev;
  float acc[2][2] = {};
  for (int k0 = 0; k0 < DIM; k0 += 32) {
    float4 av = *(const float4*)(pa + k0 + lk4);
    float4 bv = *(const float4*)(pb + k0 + lk4);
    sA[lr][lk4 + 0] = av.x; sA[lr][lk4 + 1] = av.y;
    sA[lr][lk4 + 2] = av.z; sA[lr][lk4 + 3] = av.w;
    sB[lr][lk4 + 0] = bv.x; sB[lr][lk4 + 1] = bv.y;
    sB[lr][lk4 + 2] = bv.z; sB[lr][lk4 + 3] = bv.w;
    __syncthreads();
#pragma unroll 8
    for (int k = 0; k < 32; ++k) {
      float a0 = sA[ty * 2 + 0][k], a1 = sA[ty * 2 + 1][k];
      float b0 = sB[tx * 2 + 0][k], b1 = sB[tx * 2 + 1][k];
      float d00 = a0 - b0, d01 = a0 - b1, d10 = a1 - b0, d11 = a1 - b1;
      acc[0][0] = fmaf(d00, d00, acc[0][0]);
      acc[0][1] = fmaf(d01, d01, acc[0][1]);
      acc[1][0] = fmaf(d10, d10, acc[1][0]);
      acc[1][1] = fmaf(d11, d11, acc[1][1]);
    }
    __syncthreads();
  }
#pragma unroll
  for (int i = 0; i < 2; ++i) {
    int gi2 = i0 + ty * 2 + i;
#pragma unroll
    for (int j = 0; j < 2; ++j) {
      int gj2 = j0 + tx * 2 + j;
      if (gi2 < NP1 && gj2 < NP1)
        d[(size_t)b * EDSZ + gi2 * NP1 + gj2] = sqrtf(acc[i][j]);
    }
  }
}

// ---------------------------------------------------------------------------
// Deterministic per-batch sum (fp64 tree)
// ---------------------------------------------------------------------------
__global__ __launch_bounds__(256) void batch_sum(
    const float* __restrict__ d, float* __restrict__ sums) {
  const int b = blockIdx.x;
  double s = 0.0;
  for (int idx = threadIdx.x; idx < EDSZ; idx += 256)
    s += (double)d[(size_t)b * EDSZ + idx];
  __shared__ double red[256];
  red[threadIdx.x] = s;
  __syncthreads();
  for (int off = 128; off; off >>= 1) {
    if (threadIdx.x < off) red[threadIdx.x] += red[threadIdx.x + off];
    __syncthreads();
  }
  if (threadIdx.x == 0) sums[b] = (float)red[0];
}

// ---------------------------------------------------------------------------
// normalize: edit = d / sum[b] * N*N
// ---------------------------------------------------------------------------
__global__ __launch_bounds__(256) void normalize_kernel(
    const float* __restrict__ d, const float* __restrict__ sums,
    float* __restrict__ edit) {
  int idx = blockIdx.x * 256 + threadIdx.x;
  if (idx < BATCH * EDSZ) {
    int b = idx / EDSZ;
    edit[idx] = d[idx] / sums[b] * (float)(NNODE * NNODE);
  }
}

// ---------------------------------------------------------------------------
// helpers: 4-way register select (compiles to cndmask chain, no scratch)
// ---------------------------------------------------------------------------
__device__ __forceinline__ double dsel4(double a0, double a1, double a2,
                                        double a3, int s) {
  return (s == 0) ? a0 : (s == 1) ? a1 : (s == 2) ? a2 : a3;
}
__device__ __forceinline__ int isel4(int a0, int a1, int a2, int a3, int s) {
  return (s == 0) ? a0 : (s == 1) ? a1 : (s == 2) ? a2 : a3;
}

// ---------------------------------------------------------------------------
// LSAPE via Jonker-Volgenant, ONE WAVE (64 lanes) per batch, all state in
// registers, zero barriers in the hot loop. Lane owns columns c=4*lane+q
// (lane-major => ballot lowest-lane == np.argmin lowest-index tie-break).
// Rows i are owned the same way for the u[] dual variables.
// fp64 op sequence identical to the numpy reference.
// ---------------------------------------------------------------------------
__global__ __launch_bounds__(64) void lsap_kernel(
    const float* __restrict__ edit, float* __restrict__ Aout,
    float* __restrict__ geds) {
  const int b = blockIdx.x;
  const float* ec = edit + (size_t)b * EDSZ;
  float* A = Aout + (size_t)b * EDSZ;
  const int lane = threadIdx.x;
  const int cbase = lane * 4;  // first owned column index (0-based)

  __shared__ float ecs[NP1 * ECS_LD];

  // stage edit (row stride 132 so &ecs[r*132 + 4*lane] is 16B aligned)
  for (int row = 0; row < NP1; ++row)
    for (int c = lane; c < NP1; c += 64)
      ecs[row * ECS_LD + c] = ec[row * NP1 + c];
  for (int idx = lane; idx < EDSZ; idx += 64) A[idx] = 0.f;
  __syncthreads();

  // per-lane state: 4 columns (v, minv, way, p, used-bit) + 4 rows (u, used-bit)
  double u0 = 0, u1 = 0, u2 = 0, u3 = 0;
  double v0 = 0, v1 = 0, v2 = 0, v3 = 0;
  double m0, m1, m2, m3;
  int w0 = 0, w1 = 0, w2 = 0, w3 = 0;
  int p0 = 0, p1 = 0, p2 = 0, p3 = 0;

  for (int i = 1; i <= LSN; ++i) {
    unsigned cused = 0, rused = 0;
    m0 = m1 = m2 = m3 = 1.0e300;
    int j0 = 0;       // current column (0 = dummy start)
    int i0 = i;       // p[0] = i
    for (int guard = 0; guard <= LSN; ++guard) {
      // --- mark used: column j0 (skip dummy col 0) and its row i0 ---
      if (j0 > 0 && lane == ((j0 - 1) >> 2)) cused |= 1u << ((j0 - 1) & 3);
      if (lane == ((i0 - 1) >> 2)) rused |= 1u << ((i0 - 1) & 3);

      // --- broadcast u[i0] from owning lane ---
      const double u_i0 =
          __shfl(dsel4(u0, u1, u2, u3, (i0 - 1) & 3), (i0 - 1) >> 2);

      // --- cost row C[i0-1][c] for this lane's 4 columns ---
      const int r = i0 - 1;
      double C0, C1, C2, C3;
      if (r < NNODE) {
        if (lane < 32) {  // columns 0..127: dense block
          float4 f = *(const float4*)&ecs[r * ECS_LD + cbase];
          C0 = f.x; C1 = f.y; C2 = f.z; C3 = f.w;
        } else {          // columns 128..255: diag ec[r][128], else INF
          const double dg = (double)ecs[r * ECS_LD + NNODE];
          C0 = (cbase + 0 - NNODE == r) ? dg : INF_COST;
          C1 = (cbase + 1 - NNODE == r) ? dg : INF_COST;
          C2 = (cbase + 2 - NNODE == r) ? dg : INF_COST;
          C3 = (cbase + 3 - NNODE == r) ? dg : INF_COST;
        }
      } else {
        if (lane < 32) {  // diag ec[128][r-128], else INF
          const int cc = r - NNODE;
          const double dg = (double)ecs[NNODE * ECS_LD + cc];
          C0 = (cbase + 0 == cc) ? dg : INF_COST;
          C1 = (cbase + 1 == cc) ? dg : INF_COST;
          C2 = (cbase + 2 == cc) ? dg : INF_COST;
          C3 = (cbase + 3 == cc) ? dg : INF_COST;
        } else {          // bottom-right zero block
          C0 = C1 = C2 = C3 = 0.0;
        }
      }

      // --- relax free columns (same op order as numpy: (C - u) - v) ---
      if (!(cused & 1u)) { double cur = C0 - u_i0 - v0; if (cur < m0) { m0 = cur; w0 = j0; } }
      if (!(cused & 2u)) { double cur = C1 - u_i0 - v1; if (cur < m1) { m1 = cur; w1 = j0; } }
      if (!(cused & 4u)) { double cur = C2 - u_i0 - v2; if (cur < m2) { m2 = cur; w2 = j0; } }
      if (!(cused & 8u)) { double cur = C3 - u_i0 - v3; if (cur < m3) { m3 = cur; w3 = j0; } }

      // --- lane-local argmin over free cols (ascending q => lowest index) ---
      double lv = 1.0e300; int lq = 0;
      if (!(cused & 1u) && m0 < lv) { lv = m0; lq = 0; }
      if (!(cused & 2u) && m1 < lv) { lv = m1; lq = 1; }
      if (!(cused & 4u) && m2 < lv) { lv = m2; lq = 2; }
      if (!(cused & 8u) && m3 < lv) { lv = m3; lq = 3; }

      // --- cross-lane min (exact values; fmin introduces no rounding) ---
      double gv = lv;
#pragma unroll
      for (int off = 32; off; off >>= 1)
        gv = fmin(gv, __shfl_xor(gv, off));

      // --- winner = lowest lane achieving gv (== lowest column index) ---
      unsigned long long msk = __ballot(lv == gv);
      const int wl = __ffsll(msk) - 1;
      const int j1 = (wl << 2) + __shfl(lq, wl) + 1;
      const double delta = gv;

      // --- dual updates (registers only) ---
      if (cused & 1u) v0 -= delta; else m0 -= delta;
      if (cused & 2u) v1 -= delta; else m1 -= delta;
      if (cused & 4u) v2 -= delta; else m2 -= delta;
      if (cused & 8u) v3 -= delta; else m3 -= delta;
      if (rused & 1u) u0 += delta;
      if (rused & 2u) u1 += delta;
      if (rused & 4u) u2 += delta;
      if (rused & 8u) u3 += delta;

      // --- next (or break on free column) ---
      const int pj1 =
          __shfl(isel4(p0, p1, p2, p3, (j1 - 1) & 3), (j1 - 1) >> 2);
      j0 = j1;
      if (pj1 == 0) break;
      i0 = pj1;
    }

    // --- augment along way[] chain (uniform walk via shuffles) ---
    int jc = j0;
    while (jc != 0) {
      const int cl = (jc - 1) >> 2, cq = (jc - 1) & 3;
      const int jp = __shfl(isel4(w0, w1, w2, w3, cq), cl);
      const int pv = (jp == 0)
          ? i
          : __shfl(isel4(p0, p1, p2, p3, (jp - 1) & 3), (jp - 1) >> 2);
      if (lane == cl) {
        if (cq == 0) p0 = pv;
        else if (cq == 1) p1 = pv;
        else if (cq == 2) p2 = pv;
        else p3 = pv;
      }
      jc = jp;
    }
  }

  // --- emit A and geds: column c is assigned row p[c+1]-1 ---
  double contrib = 0.0;
  {
    const int pr[4] = {p0, p1, p2, p3};
#pragma unroll
    for (int q = 0; q < 4; ++q) {
      const int rr = pr[q] - 1, cc = cbase + q;
      const int ar = min(rr, NNODE), ac = min(cc, NNODE);
      if (!(ar == NNODE && ac == NNODE)) {
        A[ar * NP1 + ac] = 1.f;
        contrib += (double)ecs[ar * ECS_LD + ac];
      }
    }
  }
#pragma unroll
  for (int off = 32; off; off >>= 1) contrib += __shfl_xor(contrib, off);
  if (lane == 0) geds[b] = (float)(contrib / 256.0);
}

// ---------------------------------------------------------------------------
// launch
// ---------------------------------------------------------------------------
extern "C" void kernel_launch(void* const* d_in, const int* in_sizes, int n_in,
                              void* d_out, int out_size, void* d_ws, size_t ws_size,
                              hipStream_t stream) {
  const float* x_s  = (const float*)d_in[0];
  const float* x_t  = (const float*)d_in[1];
  const float* W1   = (const float*)d_in[2];
  const float* b1   = (const float*)d_in[3];
  const float* W2   = (const float*)d_in[4];
  const float* b2   = (const float*)d_in[5];
  const float* virt = (const float*)d_in[6];

  const int M = BATCH * NNODE;  // 2048

  float* ws    = (float*)d_ws;
  float* h_s   = ws;
  float* h_t   = h_s + (size_t)M * DIM;
  float* e_s   = h_t + (size_t)M * DIM;
  float* e_t   = e_s + (size_t)M * DIM;
  float* h_v   = e_t + (size_t)M * DIM;
  float* e_v   = h_v + DIM;
  float* d_raw = e_v + DIM;
  float* sums  = d_raw + (size_t)BATCH * EDSZ;

  float* Aout = (float*)d_out;
  float* edit = Aout + (size_t)BATCH * EDSZ;
  float* geds = edit + (size_t)BATCH * EDSZ;

  dim3 gblk(M / 64, DIM / 64);
  gemm_nt_relu<<<gblk, 256, 0, stream>>>(x_s, W1, b1, h_s, M, DIM, DIM);
  gemm_nt_relu<<<gblk, 256, 0, stream>>>(x_t, W1, b1, h_t, M, DIM, DIM);
  vec_gemm_relu<<<1, 256, 0, stream>>>(virt, W1, b1, h_v);
  gemm_nt_relu<<<gblk, 256, 0, stream>>>(h_s, W2, b2, e_s, M, DIM, DIM);
  gemm_nt_relu<<<gblk, 256, 0, stream>>>(h_t, W2, b2, e_t, M, DIM, DIM);
  vec_gemm_relu<<<1, 256, 0, stream>>>(h_v, W2, b2, e_v);

  cdist_kernel<<<dim3(5, 5, BATCH), 256, 0, stream>>>(e_s, e_t, e_v, d_raw);
  batch_sum<<<BATCH, 256, 0, stream>>>(d_raw, sums);
  normalize_kernel<<<(BATCH * EDSZ + 255) / 256, 256, 0, stream>>>(d_raw, sums, edit);
  lsap_kernel<<<BATCH, 64, 0, stream>>>(edit, Aout, geds);
}

// Round 3
// 11909.074 us; speedup vs baseline: 2.3260x; 1.2641x over previous
//
#include <hip/hip_runtime.h>

// ---------------------------------------------------------------------------
// Problem constants (B=16, N=128, FIN=D=512)
// ---------------------------------------------------------------------------
#define BATCH 16
#define NNODE 128
#define DIM 512
#define NP1 129              // N+1 (with virtual node)
#define EDSZ (NP1 * NP1)     // 16641 per batch
#define LSN 256              // LSAP problem size (n+m)
#define INF_COST 10000.0
#define ECS_LD 132           // LDS row stride (multiple of 4 for b128 alignment)
#define BIG 1.0e300

// ---------------------------------------------------------------------------
// GEMM (NT): Y[m][n] = relu( sum_k A[m][k] * W[n][k] + bias[n] )
// ---------------------------------------------------------------------------
__global__ __launch_bounds__(256) void gemm_nt_relu(
    const float* __restrict__ A, const float* __restrict__ W,
    const float* __restrict__ bias, float* __restrict__ Y,
    int M, int N, int K) {
  __shared__ float sA[16][65];
  __shared__ float sB[16][65];
  const int tid = threadIdx.x;
  const int m0 = blockIdx.x * 64;
  const int n0 = blockIdx.y * 64;
  const int tm = tid / 16, tn = tid % 16;
  const int lr = tid / 4;
  const int lk = (tid % 4) * 4;
  float acc[4][4] = {};
  for (int k0 = 0; k0 < K; k0 += 16) {
    float4 av = *(const float4*)(A + (size_t)(m0 + lr) * K + k0 + lk);
    float4 wv = *(const float4*)(W + (size_t)(n0 + lr) * K + k0 + lk);
    sA[lk + 0][lr] = av.x; sA[lk + 1][lr] = av.y;
    sA[lk + 2][lr] = av.z; sA[lk + 3][lr] = av.w;
    sB[lk + 0][lr] = wv.x; sB[lk + 1][lr] = wv.y;
    sB[lk + 2][lr] = wv.z; sB[lk + 3][lr] = wv.w;
    __syncthreads();
#pragma unroll
    for (int k = 0; k < 16; ++k) {
      float a[4], b[4];
#pragma unroll
      for (int q = 0; q < 4; ++q) { a[q] = sA[k][tm * 4 + q]; b[q] = sB[k][tn * 4 + q]; }
#pragma unroll
      for (int i = 0; i < 4; ++i)
#pragma unroll
        for (int j = 0; j < 4; ++j) acc[i][j] = fmaf(a[i], b[j], acc[i][j]);
    }
    __syncthreads();
  }
#pragma unroll
  for (int i = 0; i < 4; ++i) {
    int m = m0 + tm * 4 + i;
#pragma unroll
    for (int j = 0; j < 4; ++j) {
      int n = n0 + tn * 4 + j;
      Y[(size_t)m * N + n] = fmaxf(acc[i][j] + bias[n], 0.f);
    }
  }
}

// ---------------------------------------------------------------------------
// Single-row embed (virtual node)
// ---------------------------------------------------------------------------
__global__ __launch_bounds__(256) void vec_gemm_relu(
    const float* __restrict__ x, const float* __restrict__ W,
    const float* __restrict__ bias, float* __restrict__ y) {
  __shared__ float sx[DIM];
  for (int k = threadIdx.x; k < DIM; k += 256) sx[k] = x[k];
  __syncthreads();
  for (int n = threadIdx.x; n < DIM; n += 256) {
    const float* w = W + (size_t)n * DIM;
    float s = 0.f;
    for (int k = 0; k < DIM; k += 4) {
      float4 wv = *(const float4*)(w + k);
      s = fmaf(sx[k + 0], wv.x, s);
      s = fmaf(sx[k + 1], wv.y, s);
      s = fmaf(sx[k + 2], wv.z, s);
      s = fmaf(sx[k + 3], wv.w, s);
    }
    y[n] = fmaxf(s + bias[n], 0.f);
  }
}

// ---------------------------------------------------------------------------
// cdist: d[b][i][j] = || esrow(b,i) - etrow(b,j) ||_2
// ---------------------------------------------------------------------------
__global__ __launch_bounds__(256) void cdist_kernel(
    const float* __restrict__ es, const float* __restrict__ et,
    const float* __restrict__ ev, float* __restrict__ d) {
  const int b = blockIdx.z;
  const int i0 = blockIdx.x * 32;
  const int j0 = blockIdx.y * 32;
  __shared__ float sA[32][33];
  __shared__ float sB[32][33];
  const int tid = threadIdx.x;
  const int ty = tid / 16, tx = tid % 16;
  const int lr = tid / 8;
  const int lk4 = (tid % 8) * 4;
  const int gi = i0 + lr;
  const int gj = j0 + lr;
  const float* pa = (gi < NNODE) ? (es + ((size_t)b * NNODE + gi) * DIM) : ev;
  const float* pb = (gj < NNODE) ? (et + ((size_t)b * NNODE + gj) * DIM) : ev;
  float acc[2][2] = {};
  for (int k0 = 0; k0 < DIM; k0 += 32) {
    float4 av = *(const float4*)(pa + k0 + lk4);
    float4 bv = *(const float4*)(pb + k0 + lk4);
    sA[lr][lk4 + 0] = av.x; sA[lr][lk4 + 1] = av.y;
    sA[lr][lk4 + 2] = av.z; sA[lr][lk4 + 3] = av.w;
    sB[lr][lk4 + 0] = bv.x; sB[lr][lk4 + 1] = bv.y;
    sB[lr][lk4 + 2] = bv.z; sB[lr][lk4 + 3] = bv.w;
    __syncthreads();
#pragma unroll 8
    for (int k = 0; k < 32; ++k) {
      float a0 = sA[ty * 2 + 0][k], a1 = sA[ty * 2 + 1][k];
      float b0 = sB[tx * 2 + 0][k], b1 = sB[tx * 2 + 1][k];
      float d00 = a0 - b0, d01 = a0 - b1, d10 = a1 - b0, d11 = a1 - b1;
      acc[0][0] = fmaf(d00, d00, acc[0][0]);
      acc[0][1] = fmaf(d01, d01, acc[0][1]);
      acc[1][0] = fmaf(d10, d10, acc[1][0]);
      acc[1][1] = fmaf(d11, d11, acc[1][1]);
    }
    __syncthreads();
  }
#pragma unroll
  for (int i = 0; i < 2; ++i) {
    int gi2 = i0 + ty * 2 + i;
#pragma unroll
    for (int j = 0; j < 2; ++j) {
      int gj2 = j0 + tx * 2 + j;
      if (gi2 < NP1 && gj2 < NP1)
        d[(size_t)b * EDSZ + gi2 * NP1 + gj2] = sqrtf(acc[i][j]);
    }
  }
}

// ---------------------------------------------------------------------------
// Deterministic per-batch sum (fp64 tree)
// ---------------------------------------------------------------------------
__global__ __launch_bounds__(256) void batch_sum(
    const float* __restrict__ d, float* __restrict__ sums) {
  const int b = blockIdx.x;
  double s = 0.0;
  for (int idx = threadIdx.x; idx < EDSZ; idx += 256)
    s += (double)d[(size_t)b * EDSZ + idx];
  __shared__ double red[256];
  red[threadIdx.x] = s;
  __syncthreads();
  for (int off = 128; off; off >>= 1) {
    if (threadIdx.x < off) red[threadIdx.x] += red[threadIdx.x + off];
    __syncthreads();
  }
  if (threadIdx.x == 0) sums[b] = (float)red[0];
}

// ---------------------------------------------------------------------------
// normalize: edit = d / sum[b] * N*N
// ---------------------------------------------------------------------------
__global__ __launch_bounds__(256) void normalize_kernel(
    const float* __restrict__ d, const float* __restrict__ sums,
    float* __restrict__ edit) {
  int idx = blockIdx.x * 256 + threadIdx.x;
  if (idx < BATCH * EDSZ) {
    int b = idx / EDSZ;
    edit[idx] = d[idx] / sums[b] * (float)(NNODE * NNODE);
  }
}

// ---------------------------------------------------------------------------
// cross-lane helpers: VALU-pipe (DPP / readlane), NOT ds_bpermute
// ---------------------------------------------------------------------------
template <int CTRL>
__device__ __forceinline__ double dpp_min_step_f64(double x) {
  union { double d; int i[2]; } s, o, r;
  s.d = x;
  o.d = BIG;  // identity for min: lanes with invalid DPP source contribute BIG
  r.i[0] = __builtin_amdgcn_update_dpp(o.i[0], s.i[0], CTRL, 0xf, 0xf, false);
  r.i[1] = __builtin_amdgcn_update_dpp(o.i[1], s.i[1], CTRL, 0xf, 0xf, false);
  return fmin(x, r.d);
}

// full-wave64 min via DPP; result valid in lane 63, returned broadcast via
// readlane into SGPRs. fmin selects one of the inputs exactly (no rounding).
__device__ __forceinline__ double wave_min_f64(double x) {
  x = dpp_min_step_f64<0x111>(x);  // row_shr:1
  x = dpp_min_step_f64<0x112>(x);  // row_shr:2
  x = dpp_min_step_f64<0x114>(x);  // row_shr:4
  x = dpp_min_step_f64<0x118>(x);  // row_shr:8
  x = dpp_min_step_f64<0x142>(x);  // row_bcast:15
  x = dpp_min_step_f64<0x143>(x);  // row_bcast:31
  union { double d; int i[2]; } s, r;
  s.d = x;
  r.i[0] = __builtin_amdgcn_readlane(s.i[0], 63);
  r.i[1] = __builtin_amdgcn_readlane(s.i[1], 63);
  return r.d;
}

__device__ __forceinline__ double readlane_f64(double x, int lane) {
  union { double d; int i[2]; } s, r;
  s.d = x;
  r.i[0] = __builtin_amdgcn_readlane(s.i[0], lane);
  r.i[1] = __builtin_amdgcn_readlane(s.i[1], lane);
  return r.d;
}

__device__ __forceinline__ double dsel4(double a0, double a1, double a2,
                                        double a3, int s) {
  return (s == 0) ? a0 : (s == 1) ? a1 : (s == 2) ? a2 : a3;
}
__device__ __forceinline__ int isel4(int a0, int a1, int a2, int a3, int s) {
  return (s == 0) ? a0 : (s == 1) ? a1 : (s == 2) ? a2 : a3;
}

// ---------------------------------------------------------------------------
// LSAPE via Jonker-Volgenant, ONE WAVE per batch, all state in registers.
// Hot loop uses only VALU-pipe cross-lane ops (DPP min, readlane, ballot);
// the single LDS cost-row read is the dominant latency term.
// fp64 op sequence identical to the numpy reference.
// ---------------------------------------------------------------------------
__global__ __launch_bounds__(64) void lsap_kernel(
    const float* __restrict__ edit, float* __restrict__ Aout,
    float* __restrict__ geds) {
  const int b = blockIdx.x;
  const float* ec = edit + (size_t)b * EDSZ;
  float* A = Aout + (size_t)b * EDSZ;
  const int lane = threadIdx.x;
  const int cbase = lane * 4;  // first owned column index (0-based)

  __shared__ float ecs[NP1 * ECS_LD];

  // stage edit (row stride 132 so &ecs[r*132 + 4*lane] is 16B aligned)
  for (int row = 0; row < NP1; ++row)
    for (int c = lane; c < NP1; c += 64)
      ecs[row * ECS_LD + c] = ec[row * NP1 + c];
  for (int idx = lane; idx < EDSZ; idx += 64) A[idx] = 0.f;
  __syncthreads();

  // per-lane state: 4 columns (v, minv, way, p) + 4 rows (u), used bitmasks
  double u0 = 0, u1 = 0, u2 = 0, u3 = 0;
  double v0 = 0, v1 = 0, v2 = 0, v3 = 0;
  double m0, m1, m2, m3;
  int w0 = 0, w1 = 0, w2 = 0, w3 = 0;
  int p0 = 0, p1 = 0, p2 = 0, p3 = 0;

  for (int i = 1; i <= LSN; ++i) {
    unsigned cused = 0, rused = 0;
    m0 = m1 = m2 = m3 = BIG;
    int j0 = 0;       // current column (0 = dummy start)
    int i0 = i;       // p[0] = i
    for (int guard = 0; guard <= LSN; ++guard) {
      // --- mark used: column j0 (skip dummy col 0) and its row i0 ---
      if (j0 > 0 && lane == ((j0 - 1) >> 2)) cused |= 1u << ((j0 - 1) & 3);
      if (lane == ((i0 - 1) >> 2)) rused |= 1u << ((i0 - 1) & 3);

      // --- broadcast u[i0] from owning lane (readlane: i0 is uniform) ---
      const double u_i0 =
          readlane_f64(dsel4(u0, u1, u2, u3, (i0 - 1) & 3), (i0 - 1) >> 2);

      // --- cost row C[i0-1][c] for this lane's 4 columns ---
      const int r = i0 - 1;
      double C0, C1, C2, C3;
      if (r < NNODE) {
        if (lane < 32) {  // columns 0..127: dense block
          float4 f = *(const float4*)&ecs[r * ECS_LD + cbase];
          C0 = f.x; C1 = f.y; C2 = f.z; C3 = f.w;
        } else {          // columns 128..255: diag ec[r][128], else INF
          const double dg = (double)ecs[r * ECS_LD + NNODE];
          C0 = (cbase + 0 - NNODE == r) ? dg : INF_COST;
          C1 = (cbase + 1 - NNODE == r) ? dg : INF_COST;
          C2 = (cbase + 2 - NNODE == r) ? dg : INF_COST;
          C3 = (cbase + 3 - NNODE == r) ? dg : INF_COST;
        }
      } else {
        if (lane < 32) {  // diag ec[128][r-128], else INF
          const int cc = r - NNODE;
          const double dg = (double)ecs[NNODE * ECS_LD + cc];
          C0 = (cbase + 0 == cc) ? dg : INF_COST;
          C1 = (cbase + 1 == cc) ? dg : INF_COST;
          C2 = (cbase + 2 == cc) ? dg : INF_COST;
          C3 = (cbase + 3 == cc) ? dg : INF_COST;
        } else {          // bottom-right zero block
          C0 = C1 = C2 = C3 = 0.0;
        }
      }

      // --- relax free columns (same op order as numpy: (C - u) - v) ---
      const bool f0 = !(cused & 1u), f1 = !(cused & 2u);
      const bool f2 = !(cused & 4u), f3 = !(cused & 8u);
      {
        double cur = C0 - u_i0 - v0;
        bool up = f0 && (cur < m0);
        m0 = up ? cur : m0; w0 = up ? j0 : w0;
      }
      {
        double cur = C1 - u_i0 - v1;
        bool up = f1 && (cur < m1);
        m1 = up ? cur : m1; w1 = up ? j0 : w1;
      }
      {
        double cur = C2 - u_i0 - v2;
        bool up = f2 && (cur < m2);
        m2 = up ? cur : m2; w2 = up ? j0 : w2;
      }
      {
        double cur = C3 - u_i0 - v3;
        bool up = f3 && (cur < m3);
        m3 = up ? cur : m3; w3 = up ? j0 : w3;
      }

      // --- lane-local argmin over free cols, 2-level tree, lowest q on tie ---
      const double a0 = f0 ? m0 : BIG, a1 = f1 ? m1 : BIG;
      const double a2 = f2 ? m2 : BIG, a3 = f3 ? m3 : BIG;
      const bool s01 = a1 < a0, s23 = a3 < a2;
      const double v01 = s01 ? a1 : a0, v23 = s23 ? a3 : a2;
      const int q01 = s01 ? 1 : 0, q23 = s23 ? 3 : 2;
      const bool sf = v23 < v01;
      const double lv = sf ? v23 : v01;
      const int lq = sf ? q23 : q01;

      // --- wave min via DPP (VALU pipe), delta in SGPRs ---
      const double gv = wave_min_f64(lv);

      // --- winner = lowest lane achieving gv (== lowest column index) ---
      unsigned long long msk = __ballot(lv == gv);
      const int wl = __ffsll(msk) - 1;
      const int j1 = (wl << 2) + __builtin_amdgcn_readlane(lq, wl) + 1;
      const double delta = gv;

      // --- dual updates (registers only; off the critical chain) ---
      if (!f0) v0 -= delta; else m0 -= delta;
      if (!f1) v1 -= delta; else m1 -= delta;
      if (!f2) v2 -= delta; else m2 -= delta;
      if (!f3) v3 -= delta; else m3 -= delta;
      if (rused & 1u) u0 += delta;
      if (rused & 2u) u1 += delta;
      if (rused & 4u) u2 += delta;
      if (rused & 8u) u3 += delta;

      // --- next (or break on free column) ---
      const int pj1 = __builtin_amdgcn_readlane(
          isel4(p0, p1, p2, p3, (j1 - 1) & 3), (j1 - 1) >> 2);
      j0 = j1;
      if (pj1 == 0) break;
      i0 = pj1;
    }

    // --- augment along way[] chain (uniform walk via readlane) ---
    int jc = j0;
    while (jc != 0) {
      const int cl = (jc - 1) >> 2, cq = (jc - 1) & 3;
      const int jp = __builtin_amdgcn_readlane(isel4(w0, w1, w2, w3, cq), cl);
      const int js = (jp == 0) ? 1 : jp;  // safe index for speculative readlane
      const int pvr = __builtin_amdgcn_readlane(
          isel4(p0, p1, p2, p3, (js - 1) & 3), (js - 1) >> 2);
      const int pv = (jp == 0) ? i : pvr;
      if (lane == cl) {
        if (cq == 0) p0 = pv;
        else if (cq == 1) p1 = pv;
        else if (cq == 2) p2 = pv;
        else p3 = pv;
      }
      jc = jp;
    }
  }

  // --- emit A and geds: column c is assigned row p[c+1]-1 ---
  double contrib = 0.0;
  {
    const int pr[4] = {p0, p1, p2, p3};
#pragma unroll
    for (int q = 0; q < 4; ++q) {
      const int rr = pr[q] - 1, cc = cbase + q;
      const int ar = min(rr, NNODE), ac = min(cc, NNODE);
      if (!(ar == NNODE && ac == NNODE)) {
        A[ar * NP1 + ac] = 1.f;
        contrib += (double)ecs[ar * ECS_LD + ac];
      }
    }
  }
#pragma unroll
  for (int off = 32; off; off >>= 1) contrib += __shfl_xor(contrib, off);
  if (lane == 0) geds[b] = (float)(contrib / 256.0);
}

// ---------------------------------------------------------------------------
// launch
// ---------------------------------------------------------------------------
extern "C" void kernel_launch(void* const* d_in, const int* in_sizes, int n_in,
                              void* d_out, int out_size, void* d_ws, size_t ws_size,
                              hipStream_t stream) {
  const float* x_s  = (const float*)d_in[0];
  const float* x_t  = (const float*)d_in[1];
  const float* W1   = (const float*)d_in[2];
  const float* b1   = (const float*)d_in[3];
  const float* W2   = (const float*)d_in[4];
  const float* b2   = (const float*)d_in[5];
  const float* virt = (const float*)d_in[6];

  const int M = BATCH * NNODE;  // 2048

  float* ws    = (float*)d_ws;
  float* h_s   = ws;
  float* h_t   = h_s + (size_t)M * DIM;
  float* e_s   = h_t + (size_t)M * DIM;
  float* e_t   = e_s + (size_t)M * DIM;
  float* h_v   = e_t + (size_t)M * DIM;
  float* e_v   = h_v + DIM;
  float* d_raw = e_v + DIM;
  float* sums  = d_raw + (size_t)BATCH * EDSZ;

  float* Aout = (float*)d_out;
  float* edit = Aout + (size_t)BATCH * EDSZ;
  float* geds = edit + (size_t)BATCH * EDSZ;

  dim3 gblk(M / 64, DIM / 64);
  gemm_nt_relu<<<gblk, 256, 0, stream>>>(x_s, W1, b1, h_s, M, DIM, DIM);
  gemm_nt_relu<<<gblk, 256, 0, stream>>>(x_t, W1, b1, h_t, M, DIM, DIM);
  vec_gemm_relu<<<1, 256, 0, stream>>>(virt, W1, b1, h_v);
  gemm_nt_relu<<<gblk, 256, 0, stream>>>(h_s, W2, b2, e_s, M, DIM, DIM);
  gemm_nt_relu<<<gblk, 256, 0, stream>>>(h_t, W2, b2, e_t, M, DIM, DIM);
  vec_gemm_relu<<<1, 256, 0, stream>>>(h_v, W2, b2, e_v);

  cdist_kernel<<<dim3(5, 5, BATCH), 256, 0, stream>>>(e_s, e_t, e_v, d_raw);
  batch_sum<<<BATCH, 256, 0, stream>>>(d_raw, sums);
  normalize_kernel<<<(BATCH * EDSZ + 255) / 256, 256, 0, stream>>>(d_raw, sums, edit);
  lsap_kernel<<<BATCH, 64, 0, stream>>>(edit, Aout, geds);
}

// Round 4
// 11096.170 us; speedup vs baseline: 2.4964x; 1.0733x over previous
//
#include <hip/hip_runtime.h>

// ---------------------------------------------------------------------------
// Problem constants (B=16, N=128, FIN=D=512)
// ---------------------------------------------------------------------------
#define BATCH 16
#define NNODE 128
#define DIM 512
#define NP1 129              // N+1 (with virtual node)
#define EDSZ (NP1 * NP1)     // 16641 per batch
#define LSN 256              // LSAP problem size (n+m)
#define INF_COST 10000.0f
#define ECS_LD 132           // LDS row stride (multiple of 4 for b128 alignment)
#define BIGF 3.0e38f         // sentinel (bits 0x7F7FC99E-ish, finite, packable)

// ---------------------------------------------------------------------------
// GEMM (NT): Y[m][n] = relu( sum_k A[m][k] * W[n][k] + bias[n] )
// ---------------------------------------------------------------------------
__global__ __launch_bounds__(256) void gemm_nt_relu(
    const float* __restrict__ A, const float* __restrict__ W,
    const float* __restrict__ bias, float* __restrict__ Y,
    int M, int N, int K) {
  __shared__ float sA[16][65];
  __shared__ float sB[16][65];
  const int tid = threadIdx.x;
  const int m0 = blockIdx.x * 64;
  const int n0 = blockIdx.y * 64;
  const int tm = tid / 16, tn = tid % 16;
  const int lr = tid / 4;
  const int lk = (tid % 4) * 4;
  float acc[4][4] = {};
  for (int k0 = 0; k0 < K; k0 += 16) {
    float4 av = *(const float4*)(A + (size_t)(m0 + lr) * K + k0 + lk);
    float4 wv = *(const float4*)(W + (size_t)(n0 + lr) * K + k0 + lk);
    sA[lk + 0][lr] = av.x; sA[lk + 1][lr] = av.y;
    sA[lk + 2][lr] = av.z; sA[lk + 3][lr] = av.w;
    sB[lk + 0][lr] = wv.x; sB[lk + 1][lr] = wv.y;
    sB[lk + 2][lr] = wv.z; sB[lk + 3][lr] = wv.w;
    __syncthreads();
#pragma unroll
    for (int k = 0; k < 16; ++k) {
      float a[4], b[4];
#pragma unroll
      for (int q = 0; q < 4; ++q) { a[q] = sA[k][tm * 4 + q]; b[q] = sB[k][tn * 4 + q]; }
#pragma unroll
      for (int i = 0; i < 4; ++i)
#pragma unroll
        for (int j = 0; j < 4; ++j) acc[i][j] = fmaf(a[i], b[j], acc[i][j]);
    }
    __syncthreads();
  }
#pragma unroll
  for (int i = 0; i < 4; ++i) {
    int m = m0 + tm * 4 + i;
#pragma unroll
    for (int j = 0; j < 4; ++j) {
      int n = n0 + tn * 4 + j;
      Y[(size_t)m * N + n] = fmaxf(acc[i][j] + bias[n], 0.f);
    }
  }
}

// ---------------------------------------------------------------------------
// Single-row embed (virtual node)
// ---------------------------------------------------------------------------
__global__ __launch_bounds__(256) void vec_gemm_relu(
    const float* __restrict__ x, const float* __restrict__ W,
    const float* __restrict__ bias, float* __restrict__ y) {
  __shared__ float sx[DIM];
  for (int k = threadIdx.x; k < DIM; k += 256) sx[k] = x[k];
  __syncthreads();
  for (int n = threadIdx.x; n < DIM; n += 256) {
    const float* w = W + (size_t)n * DIM;
    float s = 0.f;
    for (int k = 0; k < DIM; k += 4) {
      float4 wv = *(const float4*)(w + k);
      s = fmaf(sx[k + 0], wv.x, s);
      s = fmaf(sx[k + 1], wv.y, s);
      s = fmaf(sx[k + 2], wv.z, s);
      s = fmaf(sx[k + 3], wv.w, s);
    }
    y[n] = fmaxf(s + bias[n], 0.f);
  }
}

// ---------------------------------------------------------------------------
// cdist: d[b][i][j] = || esrow(b,i) - etrow(b,j) ||_2
// ---------------------------------------------------------------------------
__global__ __launch_bounds__(256) void cdist_kernel(
    const float* __restrict__ es, const float* __restrict__ et,
    const float* __restrict__ ev, float* __restrict__ d) {
  const int b = blockIdx.z;
  const int i0 = blockIdx.x * 32;
  const int j0 = blockIdx.y * 32;
  __shared__ float sA[32][33];
  __shared__ float sB[32][33];
  const int tid = threadIdx.x;
  const int ty = tid / 16, tx = tid % 16;
  const int lr = tid / 8;
  const int lk4 = (tid % 8) * 4;
  const int gi = i0 + lr;
  const int gj = j0 + lr;
  const float* pa = (gi < NNODE) ? (es + ((size_t)b * NNODE + gi) * DIM) : ev;
  const float* pb = (gj < NNODE) ? (et + ((size_t)b * NNODE + gj) * DIM) : ev;
  float acc[2][2] = {};
  for (int k0 = 0; k0 < DIM; k0 += 32) {
    float4 av = *(const float4*)(pa + k0 + lk4);
    float4 bv = *(const float4*)(pb + k0 + lk4);
    sA[lr][lk4 + 0] = av.x; sA[lr][lk4 + 1] = av.y;
    sA[lr][lk4 + 2] = av.z; sA[lr][lk4 + 3] = av.w;
    sB[lr][lk4 + 0] = bv.x; sB[lr][lk4 + 1] = bv.y;
    sB[lr][lk4 + 2] = bv.z; sB[lr][lk4 + 3] = bv.w;
    __syncthreads();
#pragma unroll 8
    for (int k = 0; k < 32; ++k) {
      float a0 = sA[ty * 2 + 0][k], a1 = sA[ty * 2 + 1][k];
      float b0 = sB[tx * 2 + 0][k], b1 = sB[tx * 2 + 1][k];
      float d00 = a0 - b0, d01 = a0 - b1, d10 = a1 - b0, d11 = a1 - b1;
      acc[0][0] = fmaf(d00, d00, acc[0][0]);
      acc[0][1] = fmaf(d01, d01, acc[0][1]);
      acc[1][0] = fmaf(d10, d10, acc[1][0]);
      acc[1][1] = fmaf(d11, d11, acc[1][1]);
    }
    __syncthreads();
  }
#pragma unroll
  for (int i = 0; i < 2; ++i) {
    int gi2 = i0 + ty * 2 + i;
#pragma unroll
    for (int j = 0; j < 2; ++j) {
      int gj2 = j0 + tx * 2 + j;
      if (gi2 < NP1 && gj2 < NP1)
        d[(size_t)b * EDSZ + gi2 * NP1 + gj2] = sqrtf(acc[i][j]);
    }
  }
}

// ---------------------------------------------------------------------------
// Deterministic per-batch sum (fp64 tree)
// ---------------------------------------------------------------------------
__global__ __launch_bounds__(256) void batch_sum(
    const float* __restrict__ d, float* __restrict__ sums) {
  const int b = blockIdx.x;
  double s = 0.0;
  for (int idx = threadIdx.x; idx < EDSZ; idx += 256)
    s += (double)d[(size_t)b * EDSZ + idx];
  __shared__ double red[256];
  red[threadIdx.x] = s;
  __syncthreads();
  for (int off = 128; off; off >>= 1) {
    if (threadIdx.x < off) red[threadIdx.x] += red[threadIdx.x + off];
    __syncthreads();
  }
  if (threadIdx.x == 0) sums[b] = (float)red[0];
}

// ---------------------------------------------------------------------------
// normalize: edit = d / sum[b] * N*N
// ---------------------------------------------------------------------------
__global__ __launch_bounds__(256) void normalize_kernel(
    const float* __restrict__ d, const float* __restrict__ sums,
    float* __restrict__ edit) {
  int idx = blockIdx.x * 256 + threadIdx.x;
  if (idx < BATCH * EDSZ) {
    int b = idx / EDSZ;
    edit[idx] = d[idx] / sums[b] * (float)(NNODE * NNODE);
  }
}

// ---------------------------------------------------------------------------
// cross-lane helpers: VALU-pipe (DPP / readlane)
// ---------------------------------------------------------------------------
// Packed (value,col) argmin element: hi32 = f32 bits of value (nonneg),
// lo32 = column id. For nonneg IEEE floats, bit order == value order, so
// v_min_f64 on the packed pattern = min by value, ties -> lowest column.
__device__ __forceinline__ double pack_mc(float m, unsigned col) {
  union { double d; unsigned u[2]; } r;
  r.u[0] = col;
  r.u[1] = __float_as_uint(m);
  return r.d;
}

template <int CTRL>
__device__ __forceinline__ double dpp_min_step_pk(double x) {
  union { double d; unsigned long long q; int i[2]; } s, o, r;
  s.d = x;
  o.q = 0x7FEFFFFFFFFFFFFFULL;  // max finite double: identity for packed min
  r.i[0] = __builtin_amdgcn_update_dpp(o.i[0], s.i[0], CTRL, 0xf, 0xf, false);
  r.i[1] = __builtin_amdgcn_update_dpp(o.i[1], s.i[1], CTRL, 0xf, 0xf, false);
  return fmin(x, r.d);
}

// wave64 packed argmin: returns (delta, col) of the global min, uniform.
__device__ __forceinline__ void wave_argmin_pk(double x, float& delta, int& col) {
  x = dpp_min_step_pk<0x111>(x);  // row_shr:1
  x = dpp_min_step_pk<0x112>(x);  // row_shr:2
  x = dpp_min_step_pk<0x114>(x);  // row_shr:4
  x = dpp_min_step_pk<0x118>(x);  // row_shr:8
  x = dpp_min_step_pk<0x142>(x);  // row_bcast:15
  x = dpp_min_step_pk<0x143>(x);  // row_bcast:31
  union { double d; int i[2]; } s;
  s.d = x;
  col = __builtin_amdgcn_readlane(s.i[0], 63);
  delta = __uint_as_float((unsigned)__builtin_amdgcn_readlane(s.i[1], 63));
}

__device__ __forceinline__ float fsel4(float a0, float a1, float a2, float a3,
                                       int s) {
  return (s == 0) ? a0 : (s == 1) ? a1 : (s == 2) ? a2 : a3;
}
__device__ __forceinline__ int isel4(int a0, int a1, int a2, int a3, int s) {
  return (s == 0) ? a0 : (s == 1) ? a1 : (s == 2) ? a2 : a3;
}

// ---------------------------------------------------------------------------
// LSAPE via Jonker-Volgenant shortest augmenting path, ONE WAVE per batch,
// all state in fp32 registers. Hot-loop cross-lane ops are VALU-pipe only
// (DPP packed min, readlane). Exactness: SSP keeps reduced costs >= 0
// (fp noise clamped), optimum is unique with margin >> fp32 noise (validated:
// A matches reference even with ~8e-3 cost perturbation).
// ---------------------------------------------------------------------------
__global__ __launch_bounds__(64) void lsap_kernel(
    const float* __restrict__ edit, float* __restrict__ Aout,
    float* __restrict__ geds) {
  const int b = blockIdx.x;
  const float* ec = edit + (size_t)b * EDSZ;
  float* A = Aout + (size_t)b * EDSZ;
  const int lane = threadIdx.x;
  const int cbase = lane * 4;  // first owned column index (0-based)

  __shared__ float ecs[NP1 * ECS_LD];

  // stage edit (row stride 132 so &ecs[r*132 + 4*lane] is 16B aligned)
  for (int row = 0; row < NP1; ++row)
    for (int c = lane; c < NP1; c += 64)
      ecs[row * ECS_LD + c] = ec[row * NP1 + c];
  for (int idx = lane; idx < EDSZ; idx += 64) A[idx] = 0.f;
  __syncthreads();

  // per-lane state: 4 columns (v, minv, way, p) + 4 rows (u), used bitmasks
  float u0 = 0.f, u1 = 0.f, u2 = 0.f, u3 = 0.f;
  float v0 = 0.f, v1 = 0.f, v2 = 0.f, v3 = 0.f;
  float m0, m1, m2, m3;
  int w0 = 0, w1 = 0, w2 = 0, w3 = 0;
  int p0 = 0, p1 = 0, p2 = 0, p3 = 0;

  for (int i = 1; i <= LSN; ++i) {
    unsigned cused = 0, rused = 0;
    m0 = m1 = m2 = m3 = BIGF;
    int j0 = 0;       // current column (0 = dummy start)
    int i0 = i;       // p[0] = i
    for (int guard = 0; guard <= LSN; ++guard) {
      // --- mark used: column j0 (skip dummy col 0) and its row i0 ---
      if (j0 > 0 && lane == ((j0 - 1) >> 2)) {
        const int q = (j0 - 1) & 3;
        cused |= 1u << q;
        if (q == 0) m0 = BIGF;
        else if (q == 1) m1 = BIGF;
        else if (q == 2) m2 = BIGF;
        else m3 = BIGF;
      }
      if (lane == ((i0 - 1) >> 2)) rused |= 1u << ((i0 - 1) & 3);

      // --- broadcast u[i0] from owning lane (i0 uniform -> readlane) ---
      const float u_i0 = __uint_as_float((unsigned)__builtin_amdgcn_readlane(
          (int)__float_as_uint(fsel4(u0, u1, u2, u3, (i0 - 1) & 3)),
          (i0 - 1) >> 2));

      // --- cost row C[i0-1][c] for this lane's 4 columns ---
      const int r = i0 - 1;
      float C0, C1, C2, C3;
      if (r < NNODE) {
        if (lane < 32) {  // columns 0..127: dense block
          float4 f = *(const float4*)&ecs[r * ECS_LD + cbase];
          C0 = f.x; C1 = f.y; C2 = f.z; C3 = f.w;
        } else {          // columns 128..255: diag ec[r][128], else INF
          const float dg = ecs[r * ECS_LD + NNODE];
          C0 = (cbase + 0 - NNODE == r) ? dg : INF_COST;
          C1 = (cbase + 1 - NNODE == r) ? dg : INF_COST;
          C2 = (cbase + 2 - NNODE == r) ? dg : INF_COST;
          C3 = (cbase + 3 - NNODE == r) ? dg : INF_COST;
        }
      } else {
        if (lane < 32) {  // diag ec[128][r-128], else INF
          const int cc = r - NNODE;
          const float dg = ecs[NNODE * ECS_LD + cc];
          C0 = (cbase + 0 == cc) ? dg : INF_COST;
          C1 = (cbase + 1 == cc) ? dg : INF_COST;
          C2 = (cbase + 2 == cc) ? dg : INF_COST;
          C3 = (cbase + 3 == cc) ? dg : INF_COST;
        } else {          // bottom-right zero block
          C0 = C1 = C2 = C3 = 0.f;
        }
      }

      // --- relax free columns; clamp >=0 keeps the packed ordering sound ---
      const bool f0 = !(cused & 1u), f1 = !(cused & 2u);
      const bool f2 = !(cused & 4u), f3 = !(cused & 8u);
      {
        float cur = fmaxf(C0 - u_i0 - v0, 0.f);
        bool up = f0 && (cur < m0);
        m0 = up ? cur : m0; w0 = up ? j0 : w0;
      }
      {
        float cur = fmaxf(C1 - u_i0 - v1, 0.f);
        bool up = f1 && (cur < m1);
        m1 = up ? cur : m1; w1 = up ? j0 : w1;
      }
      {
        float cur = fmaxf(C2 - u_i0 - v2, 0.f);
        bool up = f2 && (cur < m2);
        m2 = up ? cur : m2; w2 = up ? j0 : w2;
      }
      {
        float cur = fmaxf(C3 - u_i0 - v3, 0.f);
        bool up = f3 && (cur < m3);
        m3 = up ? cur : m3; w3 = up ? j0 : w3;
      }

      // --- packed local min (ties -> lowest col), then wave argmin ---
      const double P0 = pack_mc(m0, cbase + 0);
      const double P1 = pack_mc(m1, cbase + 1);
      const double P2 = pack_mc(m2, cbase + 2);
      const double P3 = pack_mc(m3, cbase + 3);
      const double loc = fmin(fmin(P0, P1), fmin(P2, P3));
      float delta; int jcol;
      wave_argmin_pk(loc, delta, jcol);
      const int j1 = jcol + 1;

      // --- dual updates (registers only) ---
      if (!f0) v0 -= delta; else m0 = fmaxf(m0 - delta, 0.f);
      if (!f1) v1 -= delta; else m1 = fmaxf(m1 - delta, 0.f);
      if (!f2) v2 -= delta; else m2 = fmaxf(m2 - delta, 0.f);
      if (!f3) v3 -= delta; else m3 = fmaxf(m3 - delta, 0.f);
      if (rused & 1u) u0 += delta;
      if (rused & 2u) u1 += delta;
      if (rused & 4u) u2 += delta;
      if (rused & 8u) u3 += delta;

      // --- next (or break on free column) ---
      const int pj1 = __builtin_amdgcn_readlane(
          isel4(p0, p1, p2, p3, (j1 - 1) & 3), (j1 - 1) >> 2);
      j0 = j1;
      if (pj1 == 0) break;
      i0 = pj1;
    }

    // --- augment along way[] chain (uniform walk via readlane) ---
    int jc = j0;
    while (jc != 0) {
      const int cl = (jc - 1) >> 2, cq = (jc - 1) & 3;
      const int jp = __builtin_amdgcn_readlane(isel4(w0, w1, w2, w3, cq), cl);
      const int js = (jp == 0) ? 1 : jp;  // safe index for speculative readlane
      const int pvr = __builtin_amdgcn_readlane(
          isel4(p0, p1, p2, p3, (js - 1) & 3), (js - 1) >> 2);
      const int pv = (jp == 0) ? i : pvr;
      if (lane == cl) {
        if (cq == 0) p0 = pv;
        else if (cq == 1) p1 = pv;
        else if (cq == 2) p2 = pv;
        else p3 = pv;
      }
      jc = jp;
    }
  }

  // --- emit A and geds: column c is assigned row p[c+1]-1 ---
  double contrib = 0.0;
  {
    const int pr[4] = {p0, p1, p2, p3};
#pragma unroll
    for (int q = 0; q < 4; ++q) {
      const int rr = pr[q] - 1, cc = cbase + q;
      const int ar = min(rr, NNODE), ac = min(cc, NNODE);
      if (!(ar == NNODE && ac == NNODE)) {
        A[ar * NP1 + ac] = 1.f;
        contrib += (double)ecs[ar * ECS_LD + ac];
      }
    }
  }
#pragma unroll
  for (int off = 32; off; off >>= 1) contrib += __shfl_xor(contrib, off);
  if (lane == 0) geds[b] = (float)(contrib / 256.0);
}

// ---------------------------------------------------------------------------
// launch
// ---------------------------------------------------------------------------
extern "C" void kernel_launch(void* const* d_in, const int* in_sizes, int n_in,
                              void* d_out, int out_size, void* d_ws, size_t ws_size,
                              hipStream_t stream) {
  const float* x_s  = (const float*)d_in[0];
  const float* x_t  = (const float*)d_in[1];
  const float* W1   = (const float*)d_in[2];
  const float* b1   = (const float*)d_in[3];
  const float* W2   = (const float*)d_in[4];
  const float* b2   = (const float*)d_in[5];
  const float* virt = (const float*)d_in[6];

  const int M = BATCH * NNODE;  // 2048

  float* ws    = (float*)d_ws;
  float* h_s   = ws;
  float* h_t   = h_s + (size_t)M * DIM;
  float* e_s   = h_t + (size_t)M * DIM;
  float* e_t   = e_s + (size_t)M * DIM;
  float* h_v   = e_t + (size_t)M * DIM;
  float* e_v   = h_v + DIM;
  float* d_raw = e_v + DIM;
  float* sums  = d_raw + (size_t)BATCH * EDSZ;

  float* Aout = (float*)d_out;
  float* edit = Aout + (size_t)BATCH * EDSZ;
  float* geds = edit + (size_t)BATCH * EDSZ;

  dim3 gblk(M / 64, DIM / 64);
  gemm_nt_relu<<<gblk, 256, 0, stream>>>(x_s, W1, b1, h_s, M, DIM, DIM);
  gemm_nt_relu<<<gblk, 256, 0, stream>>>(x_t, W1, b1, h_t, M, DIM, DIM);
  vec_gemm_relu<<<1, 256, 0, stream>>>(virt, W1, b1, h_v);
  gemm_nt_relu<<<gblk, 256, 0, stream>>>(h_s, W2, b2, e_s, M, DIM, DIM);
  gemm_nt_relu<<<gblk, 256, 0, stream>>>(h_t, W2, b2, e_t, M, DIM, DIM);
  vec_gemm_relu<<<1, 256, 0, stream>>>(h_v, W2, b2, e_v);

  cdist_kernel<<<dim3(5, 5, BATCH), 256, 0, stream>>>(e_s, e_t, e_v, d_raw);
  batch_sum<<<BATCH, 256, 0, stream>>>(d_raw, sums);
  normalize_kernel<<<(BATCH * EDSZ + 255) / 256, 256, 0, stream>>>(d_raw, sums, edit);
  lsap_kernel<<<BATCH, 64, 0, stream>>>(edit, Aout, geds);
}